// Round 4
// baseline (367.423 us; speedup 1.0000x reference)
//
#include <hip/hip_runtime.h>
#include <hip/hip_bf16.h>
#include <cstddef>

// JastrowNet, single fused kernel. Grid = 5*512 blocks x 256 threads:
//   p = bid>>9: 0..3 -> electron spin-quadrant (qi=p>>1, qj=p&1), 4 -> nuclear.
// Phase A: per-edge-row filter MLPs for BOTH layers (features loaded once).
//   Weights are read with wave-uniform indices straight from global -> the
//   compiler emits s_load into SGPRs; weight-FMAs are v_fma(v,s,v) with no
//   LDS traffic (this was the R3 bottleneck: ~320 ds_read_b128/thread).
//   Layer-1 output reduces directly to z1 partials (hx1 is spin-only);
//   layer-2 electron filters stored masked as bf16; nuclear pre-reduced vs Y.
// Phase B: last-arriving block per batch (device-scope atomic handshake on a
//   self-resetting __device__ counter) runs the tiny sequential update
//   (x1, hx2, z2, x2, readout) inline. No second kernel launch.
//
// Workspace (10,485,760 B): w2 bf16 [512][32][32][8] | z1p f32 [512][2][32][8]
//                           | zn1 f32 [512][32][8] | zn2 f32 [512][32][8]

#define NB   512
#define NE   32
#define NA   8
#define NF   32
#define NH   16
#define NK   8
#define NEMB 16

#define Z1P_OFF  8388608u
#define ZN1_OFF  (Z1P_OFF + 1048576u)
#define ZN2_OFF  (ZN1_OFF + 524288u)

__device__ int g_cnt[NB];   // zero-initialized at load; self-resetting each launch

__device__ __forceinline__ float ssp(float v){
    return fmaxf(v, 0.f) + __logf(1.f + __expf(-fabsf(v))) - 0.6931471805599453f;
}

// One 32-feature row through 32->16->8 ssp MLP. W1/B1/W2/B2 are GLOBAL
// pointers with wave-uniform addresses -> scalar loads, FMAs use SGPR operand.
__device__ __forceinline__ void compute_w(const float4 ev[8],
        const float* __restrict__ W1, const float* __restrict__ B1,
        const float* __restrict__ W2, const float* __restrict__ B2,
        float w[NK])
{
    float h1[NH];
#pragma unroll
    for (int h = 0; h < NH; h++) h1[h] = B1[h];
#pragma unroll
    for (int q = 0; q < 8; q++){
        const float e4[4] = {ev[q].x, ev[q].y, ev[q].z, ev[q].w};
#pragma unroll
        for (int c = 0; c < 4; c++){
            const float ef = e4[c];
            const float* wr = W1 + (4*q + c)*NH;
#pragma unroll
            for (int h = 0; h < NH; h++) h1[h] = fmaf(ef, wr[h], h1[h]);
        }
    }
#pragma unroll
    for (int h = 0; h < NH; h++) h1[h] = ssp(h1[h]);
    float acc[NK];
#pragma unroll
    for (int k = 0; k < NK; k++) acc[k] = B2[k];
#pragma unroll
    for (int h = 0; h < NH; h++){
        const float hv = h1[h];
        const float* wr = W2 + h*NK;
#pragma unroll
        for (int k = 0; k < NK; k++) acc[k] = fmaf(hv, wr[k], acc[k]);
    }
#pragma unroll
    for (int k = 0; k < NK; k++) w[k] = ssp(acc[k]);
}

extern "C" __global__ void __launch_bounds__(256, 4)
jastrow_fused(const float* __restrict__ edges_elec,
              const float* __restrict__ edges_nuc,
              const float* __restrict__ X_emb,
              const float* __restrict__ Yk,
              const float* __restrict__ wW1, const float* __restrict__ wb1,
              const float* __restrict__ wW2, const float* __restrict__ wb2,
              const float* __restrict__ hW,  const float* __restrict__ hb,
              const float* __restrict__ gW,  const float* __restrict__ gb,
              const float* __restrict__ orbW,
              __hip_bfloat16* __restrict__ w2,
              float* __restrict__ z1p,
              float* __restrict__ zn1, float* __restrict__ zn2,
              float* __restrict__ out)
{
    __shared__ float s_hx1[NK];      // layer-1 hx for the j-column spin (elec)
    __shared__ float s_Y[NA*NK];     // nuclear embeddings (nuc blocks)
    __shared__ float s_x[NE*NEMB];   // phase B
    __shared__ float s_z[NE*NK];
    __shared__ float s_hx[NE*NK];
    __shared__ float s_red[4];
    __shared__ int   s_last;

    const int bid = blockIdx.x, t = threadIdx.x;
    const int p = bid >> 9, b = bid & 511;
    const bool isNuc = (p == 4);
    const int qi = p >> 1, qj = p & 1;
    const int cc = isNuc ? 2 : ((qi == qj) ? 0 : 1);

    // per-channel weight bases (wave-uniform)
    const float* W1l0 = wW1 + (0*3 + cc)*NF*NH;
    const float* W1l1 = wW1 + (1*3 + cc)*NF*NH;
    const float* B1l0 = wb1 + (0*3 + cc)*NH;
    const float* B1l1 = wb1 + (1*3 + cc)*NH;
    const float* W2l0 = wW2 + (0*3 + cc)*NH*NK;
    const float* W2l1 = wW2 + (1*3 + cc)*NH*NK;
    const float* B2l0 = wb2 + (0*3 + cc)*NK;
    const float* B2l1 = wb2 + (1*3 + cc)*NK;

    // small staging
    if (isNuc){
        if (t < NA*NK) s_Y[t] = Yk[t];
    } else if (t < NK){
        // hx1[qj][k] = ssp(X_emb[qj] @ hW[0] + hb[0])  (x0 depends only on spin)
        float acc = hb[t];
#pragma unroll
        for (int e = 0; e < NEMB; e++)
            acc = fmaf(X_emb[qj*NEMB + e], hW[e*NK + t], acc);
        s_hx1[t] = ssp(acc);
    }
    __syncthreads();

    // ---- load this thread's feature row once ----
    const float* src;
    if (isNuc) src = edges_nuc + ((size_t)b*NE*NA + t) * NF;
    else {
        const int i = qi*16 + (t >> 4), j = qj*16 + (t & 15);
        src = edges_elec + ((size_t)b*NE*NE + i*NE + j) * NF;
    }
    float4 ev[8];
    {
        const float4* p4 = (const float4*)src;
#pragma unroll
        for (int q = 0; q < 8; q++) ev[q] = p4[q];
    }

    // ---- layer 1: compute filter, reduce directly ----
    {
        float w[NK];
        compute_w(ev, W1l0, B1l0, W2l0, B2l0, w);
        if (isNuc){
            const int i = t >> 3, m = t & 7;
            float pk[NK];
#pragma unroll
            for (int k = 0; k < NK; k++) pk[k] = w[k] * s_Y[m*NK + k];
#pragma unroll
            for (int off = 4; off > 0; off >>= 1)
#pragma unroll
                for (int k = 0; k < NK; k++) pk[k] += __shfl_down(pk[k], off, 8);
            if (m == 0){
#pragma unroll
                for (int k = 0; k < NK; k++) zn1[((size_t)b*NE + i)*NK + k] = pk[k];
            }
        } else {
            const int i16 = t >> 4, j16 = t & 15;
            const float msk = (cc == 0 && i16 == j16) ? 0.f : 1.f;
            float pk[NK];
#pragma unroll
            for (int k = 0; k < NK; k++) pk[k] = w[k] * msk * s_hx1[k];
#pragma unroll
            for (int off = 8; off > 0; off >>= 1)
#pragma unroll
                for (int k = 0; k < NK; k++) pk[k] += __shfl_down(pk[k], off, 16);
            if (j16 == 0){
                const int i = qi*16 + i16;
#pragma unroll
                for (int k = 0; k < NK; k++)
                    z1p[(((size_t)b*2 + qj)*NE + i)*NK + k] = pk[k];
            }
        }
    }
    // ---- layer 2: nuclear reduce / electron store bf16 ----
    {
        float w[NK];
        compute_w(ev, W1l1, B1l1, W2l1, B2l1, w);
        if (isNuc){
            const int i = t >> 3, m = t & 7;
            float pk[NK];
#pragma unroll
            for (int k = 0; k < NK; k++) pk[k] = w[k] * s_Y[m*NK + k];
#pragma unroll
            for (int off = 4; off > 0; off >>= 1)
#pragma unroll
                for (int k = 0; k < NK; k++) pk[k] += __shfl_down(pk[k], off, 8);
            if (m == 0){
#pragma unroll
                for (int k = 0; k < NK; k++) zn2[((size_t)b*NE + i)*NK + k] = pk[k];
            }
        } else {
            const int i16 = t >> 4, j16 = t & 15;
            const float msk = (cc == 0 && i16 == j16) ? 0.f : 1.f;
            const int i = qi*16 + i16, j = qj*16 + j16;
            union { __hip_bfloat16 h[8]; uint4 u; } pack;
#pragma unroll
            for (int k = 0; k < NK; k++) pack.h[k] = __float2bfloat16(w[k] * msk);
            *(uint4*)&w2[((size_t)b*NE*NE + i*NE + j)*NK] = pack.u;
        }
    }

    // ---- completion handshake: last of the 5 blocks for batch b updates ----
    __threadfence();
    __syncthreads();
    if (t == 0){
        const int old = atomicAdd(&g_cnt[b], 1);
        s_last = (old == 4) ? 1 : 0;
        if (old == 4) atomicExch(&g_cnt[b], 0);   // self-reset for next launch
    }
    __syncthreads();
    if (!s_last) return;
    __threadfence();   // acquire: other blocks' writes now visible

    // =================== Phase B: per-batch update ===================
    // 1. z1[i,k] = partials + nuclear
    s_z[t] = z1p[((size_t)b*2 + 0)*NE*NK + t]
           + z1p[((size_t)b*2 + 1)*NE*NK + t]
           + zn1[(size_t)b*NE*NK + t];
    __syncthreads();
    // 2. x1 = x0 + z1 @ gW0 + gb0   (2 entries per thread)
#pragma unroll
    for (int q = 0; q < 2; q++){
        const int idx = q*256 + t, i = idx >> 4, e = idx & 15;
        float acc = gb[e];
#pragma unroll
        for (int k = 0; k < NK; k++)
            acc = fmaf(s_z[i*NK + k], gW[k*NEMB + e], acc);
        s_x[idx] = X_emb[(i >> 4)*NEMB + e] + acc;
    }
    __syncthreads();
    // 3. hx2 = ssp(x1 @ hW1 + hb1)
    {
        const int i = t >> 3, k = t & 7;
        float acc = hb[NK + k];
#pragma unroll
        for (int e = 0; e < NEMB; e++)
            acc = fmaf(s_x[i*NEMB + e], hW[NEMB*NK + e*NK + k], acc);
        s_hx[t] = ssp(acc);
    }
    __syncthreads();
    // 4. z2[i,k] = sum_j w2[i,j,k]*hx2[j,k] + zn2[i,k]  (shuffle-free)
    {
        const int i = t >> 3, k = t & 7;
        const __hip_bfloat16* wrow = w2 + ((size_t)b*NE*NE + i*NE)*NK + k;
        float acc = zn2[(size_t)b*NE*NK + t];
#pragma unroll
        for (int j = 0; j < NE; j++)
            acc = fmaf(__bfloat162float(wrow[j*NK]), s_hx[j*NK + k], acc);
        __syncthreads();
        s_z[t] = acc;
    }
    __syncthreads();
    // 5. x2 = x1 + z2 @ gW1 + gb1
#pragma unroll
    for (int q = 0; q < 2; q++){
        const int idx = q*256 + t, i = idx >> 4, e = idx & 15;
        float acc = gb[NEMB + e];
#pragma unroll
        for (int k = 0; k < NK; k++)
            acc = fmaf(s_z[i*NK + k], gW[NK*NEMB + k*NEMB + e], acc);
        s_x[idx] += acc;
    }
    __syncthreads();
    // 6. readout
    float part = (s_x[t] + s_x[t + 256]) * orbW[t & 15];
#pragma unroll
    for (int off = 32; off > 0; off >>= 1) part += __shfl_down(part, off, 64);
    if ((t & 63) == 0) s_red[t >> 6] = part;
    __syncthreads();
    if (t == 0) out[b] = s_red[0] + s_red[1] + s_red[2] + s_red[3];
}

extern "C" void kernel_launch(void* const* d_in, const int* in_sizes, int n_in,
                              void* d_out, int out_size, void* d_ws, size_t ws_size,
                              hipStream_t stream)
{
    char* ws = (char*)d_ws;
    __hip_bfloat16* w2 = (__hip_bfloat16*)ws;
    float* z1p = (float*)(ws + Z1P_OFF);
    float* zn1 = (float*)(ws + ZN1_OFF);
    float* zn2 = (float*)(ws + ZN2_OFF);

    jastrow_fused<<<5*NB, 256, 0, stream>>>(
        (const float*)d_in[0],  (const float*)d_in[1],  (const float*)d_in[2],
        (const float*)d_in[3],  (const float*)d_in[4],  (const float*)d_in[5],
        (const float*)d_in[6],  (const float*)d_in[7],  (const float*)d_in[8],
        (const float*)d_in[9],  (const float*)d_in[10], (const float*)d_in[11],
        (const float*)d_in[12],
        w2, z1p, zn1, zn2, (float*)d_out);
}

// Round 6
// 298.966 us; speedup vs baseline: 1.2290x; 1.2290x over previous
//
#include <hip/hip_runtime.h>
#include <hip/hip_bf16.h>
#include <cstddef>

// JastrowNet, single fused kernel, R=4 row-amortized weight reads.
// Grid = 640 blocks x 256 threads:
//   bid < 512 : electron blocks. c = bid&1 (0 same, 1 anti), batch pair
//               bA = 2*(bid>>1) in [0,510]. Each thread: 4 rows =
//               {batch bA,bA+1} x {quadrant q=0,1}, (qi=q, qj=c?1-q:q),
//               (i16,j16) = (t>>4, t&15).
//   bid >= 512: nuclear blocks. bA = 4*(bid-512) in [0,508]. Each thread:
//               row t (i=t>>3, m=t&7) of 4 consecutive batches.
// (R5 crashed: grid was 1152 with bA up to 1022 -> OOB reads/writes. The
//  decomposition is only consistent with grid 640 / isNuc = bid>=512.)
// Weights live in LDS (broadcast ds_read_b128, 0 conflicts — R3-proven).
// R=4 rows share every weight read -> 1 ds_read_b128 per 16 wave-FMAs
// (R3 was 1:4), so the kernel is VALU-bound, not LDS-issue-bound.
// Layer-1 filter output reduces in-register to z1 partials (hx1 is spin-only);
// layer-2 electron filters stored masked bf16; nuclear pre-reduced vs Y.
// Last-arriving of the 3 contributor blocks per batch (device-scope atomic,
// self-resetting counter) runs the tiny sequential update inline.
//
// Workspace: w2 bf16 [512][32][32][8] | z1p f32 [512][2][32][8]
//            | zn1 f32 [512][32][8] | zn2 f32 [512][32][8]

#define NB   512
#define NE   32
#define NA   8
#define NF   32
#define NH   16
#define NK   8
#define NEMB 16

#define Z1P_OFF  8388608u
#define ZN1_OFF  (Z1P_OFF + 1048576u)
#define ZN2_OFF  (ZN1_OFF + 524288u)

__device__ int g_cnt[NB];   // zero at load; winner self-resets each launch

__device__ __forceinline__ float ssp(float v){
    return fmaxf(v, 0.f) + __logf(1.f + __expf(-fabsf(v))) - 0.6931471805599453f;
}

extern "C" __global__ void __launch_bounds__(256, 3)
jastrow_fused(const float* __restrict__ edges_elec,
              const float* __restrict__ edges_nuc,
              const float* __restrict__ X_emb,
              const float* __restrict__ Yk,
              const float* __restrict__ wW1, const float* __restrict__ wb1,
              const float* __restrict__ wW2, const float* __restrict__ wb2,
              const float* __restrict__ hW,  const float* __restrict__ hb,
              const float* __restrict__ gW,  const float* __restrict__ gb,
              const float* __restrict__ orbW,
              __hip_bfloat16* __restrict__ w2,
              float* __restrict__ z1p,
              float* __restrict__ zn1, float* __restrict__ zn2,
              float* __restrict__ out)
{
    __shared__ __align__(16) float s_W1[2*NF*NH];   // this channel, layers 0,1
    __shared__ __align__(16) float s_b1[2*NH];
    __shared__ __align__(16) float s_W2[2*NH*NK];
    __shared__ __align__(16) float s_b2[2*NK];
    __shared__ float s_hx1[2*NK];    // layer-1 hx by spin (elec blocks)
    __shared__ float s_Y[NA*NK];     // nuclear embeddings (nuc blocks)
    __shared__ float s_x[NE*NEMB];   // phase B
    __shared__ float s_z[NE*NK];
    __shared__ float s_hx[NE*NK];
    __shared__ float s_red[4];
    __shared__ int   s_win;

    const int bid = blockIdx.x, t = threadIdx.x;
    const bool isNuc = (bid >= NB);
    const int c  = bid & 1;                       // elec channel (if elec)
    const int cc = isNuc ? 2 : c;                 // weight channel index
    const int bA = isNuc ? 4*(bid - NB) : 2*(bid >> 1);

    // ---- stage channel-cc weights (both layers) into LDS ----
    for (int idx = t; idx < 2*NF*NH; idx += 256){
        const int l = idx >> 9, r = idx & 511;
        s_W1[idx] = wW1[(l*3 + cc)*NF*NH + r];
    }
    if (t < 2*NH*NK){
        const int l = t >> 7, r = t & 127;
        s_W2[t] = wW2[(l*3 + cc)*NH*NK + r];
    }
    if (t < 2*NH){ const int l = t >> 4; s_b1[t] = wb1[(l*3 + cc)*NH + (t & 15)]; }
    if (t < 2*NK){ const int l = t >> 3; s_b2[t] = wb2[(l*3 + cc)*NK + (t & 7)]; }
    if (isNuc){
        if (t < NA*NK) s_Y[t] = Yk[t];
    } else if (t < 2*NK){
        const int sp = t >> 3, k = t & 7;
        float acc = hb[k];
#pragma unroll
        for (int e = 0; e < NEMB; e++)
            acc = fmaf(X_emb[sp*NEMB + e], hW[e*NK + k], acc);
        s_hx1[t] = ssp(acc);
    }
    __syncthreads();

    // ---- per-thread row pointers (4 rows) ----
    const float* rowp[4];
    if (isNuc){
#pragma unroll
        for (int s = 0; s < 4; s++)
            rowp[s] = edges_nuc + ((size_t)(bA + s)*NE*NA + t) * NF;
    } else {
        const int i16 = t >> 4, j16 = t & 15;
#pragma unroll
        for (int s = 0; s < 4; s++){
            const int b = bA + (s >> 1), q = s & 1;
            const int qi = q, qj = c ? (1 - q) : q;
            rowp[s] = edges_elec + (((size_t)b*NE + qi*16 + i16)*NE + qj*16 + j16) * NF;
        }
    }

    // ================= Phase A: filter MLPs, both layers =================
#pragma unroll 1
    for (int l = 0; l < 2; l++){
        const float* W1 = s_W1 + l*NF*NH;
        const float* B1 = s_b1 + l*NH;
        const float* W2s = s_W2 + l*NH*NK;
        const float* B2 = s_b2 + l*NK;

        float h1[4][NH];
#pragma unroll
        for (int s = 0; s < 4; s++)
#pragma unroll
            for (int h = 0; h < NH; h++) h1[s][h] = B1[h];

#pragma unroll 2
        for (int qc = 0; qc < 8; qc++){
            float4 f[4];
#pragma unroll
            for (int s = 0; s < 4; s++)
                f[s] = ((const float4*)rowp[s])[qc];
#pragma unroll
            for (int c4 = 0; c4 < 4; c4++){
                const float4* wr = (const float4*)(W1 + (qc*4 + c4)*NH);
                const float4 w0 = wr[0], w1 = wr[1], w2v = wr[2], w3 = wr[3];
#pragma unroll
                for (int s = 0; s < 4; s++){
                    const float ef = (c4 == 0) ? f[s].x : (c4 == 1) ? f[s].y
                                   : (c4 == 2) ? f[s].z : f[s].w;
                    h1[s][ 0] = fmaf(ef, w0.x, h1[s][ 0]);
                    h1[s][ 1] = fmaf(ef, w0.y, h1[s][ 1]);
                    h1[s][ 2] = fmaf(ef, w0.z, h1[s][ 2]);
                    h1[s][ 3] = fmaf(ef, w0.w, h1[s][ 3]);
                    h1[s][ 4] = fmaf(ef, w1.x, h1[s][ 4]);
                    h1[s][ 5] = fmaf(ef, w1.y, h1[s][ 5]);
                    h1[s][ 6] = fmaf(ef, w1.z, h1[s][ 6]);
                    h1[s][ 7] = fmaf(ef, w1.w, h1[s][ 7]);
                    h1[s][ 8] = fmaf(ef, w2v.x, h1[s][ 8]);
                    h1[s][ 9] = fmaf(ef, w2v.y, h1[s][ 9]);
                    h1[s][10] = fmaf(ef, w2v.z, h1[s][10]);
                    h1[s][11] = fmaf(ef, w2v.w, h1[s][11]);
                    h1[s][12] = fmaf(ef, w3.x, h1[s][12]);
                    h1[s][13] = fmaf(ef, w3.y, h1[s][13]);
                    h1[s][14] = fmaf(ef, w3.z, h1[s][14]);
                    h1[s][15] = fmaf(ef, w3.w, h1[s][15]);
                }
            }
        }
#pragma unroll
        for (int s = 0; s < 4; s++)
#pragma unroll
            for (int h = 0; h < NH; h++) h1[s][h] = ssp(h1[s][h]);

        float acc[4][NK];
#pragma unroll
        for (int s = 0; s < 4; s++)
#pragma unroll
            for (int k = 0; k < NK; k++) acc[s][k] = B2[k];
#pragma unroll
        for (int h = 0; h < NH; h++){
            const float4* wr = (const float4*)(W2s + h*NK);
            const float4 w0 = wr[0], w1 = wr[1];
#pragma unroll
            for (int s = 0; s < 4; s++){
                const float hv = h1[s][h];
                acc[s][0] = fmaf(hv, w0.x, acc[s][0]);
                acc[s][1] = fmaf(hv, w0.y, acc[s][1]);
                acc[s][2] = fmaf(hv, w0.z, acc[s][2]);
                acc[s][3] = fmaf(hv, w0.w, acc[s][3]);
                acc[s][4] = fmaf(hv, w1.x, acc[s][4]);
                acc[s][5] = fmaf(hv, w1.y, acc[s][5]);
                acc[s][6] = fmaf(hv, w1.z, acc[s][6]);
                acc[s][7] = fmaf(hv, w1.w, acc[s][7]);
            }
        }
#pragma unroll
        for (int s = 0; s < 4; s++)
#pragma unroll
            for (int k = 0; k < NK; k++) acc[s][k] = ssp(acc[s][k]);

        // ---- consume: reduce (layer 0 / nuc both layers) or store bf16 ----
        if (isNuc){
            const int i = t >> 3, m = t & 7;
            float* zn = (l == 0) ? zn1 : zn2;
#pragma unroll
            for (int s = 0; s < 4; s++){
                float pk[NK];
#pragma unroll
                for (int k = 0; k < NK; k++) pk[k] = acc[s][k] * s_Y[m*NK + k];
#pragma unroll
                for (int off = 4; off > 0; off >>= 1)
#pragma unroll
                    for (int k = 0; k < NK; k++) pk[k] += __shfl_down(pk[k], off, 8);
                if (m == 0){
#pragma unroll
                    for (int k = 0; k < NK; k++)
                        zn[((size_t)(bA + s)*NE + i)*NK + k] = pk[k];
                }
            }
        } else {
            const int i16 = t >> 4, j16 = t & 15;
            const float msk = (c == 0 && i16 == j16) ? 0.f : 1.f;
            if (l == 0){
#pragma unroll
                for (int s = 0; s < 4; s++){
                    const int b = bA + (s >> 1), q = s & 1;
                    const int qj = c ? (1 - q) : q;
                    float pk[NK];
#pragma unroll
                    for (int k = 0; k < NK; k++)
                        pk[k] = acc[s][k] * msk * s_hx1[qj*NK + k];
#pragma unroll
                    for (int off = 8; off > 0; off >>= 1)
#pragma unroll
                        for (int k = 0; k < NK; k++) pk[k] += __shfl_down(pk[k], off, 16);
                    if (j16 == 0){
                        const int i = q*16 + i16;
#pragma unroll
                        for (int k = 0; k < NK; k++)
                            z1p[(((size_t)b*2 + c)*NE + i)*NK + k] = pk[k];
                    }
                }
            } else {
#pragma unroll
                for (int s = 0; s < 4; s++){
                    const int b = bA + (s >> 1), q = s & 1;
                    const int qi = q, qj = c ? (1 - q) : q;
                    const int i = qi*16 + i16, j = qj*16 + j16;
                    union { __hip_bfloat16 h[8]; uint4 u; } pack;
#pragma unroll
                    for (int k = 0; k < NK; k++)
                        pack.h[k] = __float2bfloat16(acc[s][k] * msk);
                    *(uint4*)&w2[((size_t)b*NE*NE + i*NE + j)*NK] = pack.u;
                }
            }
        }
    }

    // ---- completion handshake: 3 contributors per batch ----
    __threadfence();
    __syncthreads();
    if (t == 0){
        int mask = 0;
        const int nb = isNuc ? 4 : 2;
        for (int s = 0; s < nb; s++){
            const int old = atomicAdd(&g_cnt[bA + s], 1);
            if (old == 2){ mask |= 1 << s; atomicExch(&g_cnt[bA + s], 0); }
        }
        s_win = mask;
    }
    __syncthreads();
    const int mask = s_win;
    if (!mask) return;
    __threadfence();   // acquire: other contributors' writes now visible

    // ================= Phase B: per-batch sequential update =================
    for (int s = 0; s < 4; s++){
        if (!(mask & (1 << s))) continue;
        const int b = bA + s;
        // 1. z1 = partials + nuclear
        s_z[t] = z1p[((size_t)b*2 + 0)*NE*NK + t]
               + z1p[((size_t)b*2 + 1)*NE*NK + t]
               + zn1[(size_t)b*NE*NK + t];
        __syncthreads();
        // 2. x1 = x0 + z1 @ gW0 + gb0
#pragma unroll
        for (int q = 0; q < 2; q++){
            const int idx = q*256 + t, i = idx >> 4, e = idx & 15;
            float a = gb[e];
#pragma unroll
            for (int k = 0; k < NK; k++)
                a = fmaf(s_z[i*NK + k], gW[k*NEMB + e], a);
            s_x[idx] = X_emb[(i >> 4)*NEMB + e] + a;
        }
        __syncthreads();
        // 3. hx2 = ssp(x1 @ hW1 + hb1)
        {
            const int i = t >> 3, k = t & 7;
            float a = hb[NK + k];
#pragma unroll
            for (int e = 0; e < NEMB; e++)
                a = fmaf(s_x[i*NEMB + e], hW[NEMB*NK + e*NK + k], a);
            s_hx[t] = ssp(a);
        }
        __syncthreads();
        // 4. z2[i,k] = sum_j w2[i,j,k]*hx2[j,k] + zn2
        {
            const int i = t >> 3, k = t & 7;
            const __hip_bfloat16* wrow = w2 + ((size_t)b*NE*NE + i*NE)*NK + k;
            float a = zn2[(size_t)b*NE*NK + t];
#pragma unroll
            for (int j = 0; j < NE; j++)
                a = fmaf(__bfloat162float(wrow[j*NK]), s_hx[j*NK + k], a);
            s_z[t] = a;
        }
        __syncthreads();
        // 5. x2 = x1 + z2 @ gW1 + gb1
#pragma unroll
        for (int q = 0; q < 2; q++){
            const int idx = q*256 + t, i = idx >> 4, e = idx & 15;
            float a = gb[NEMB + e];
#pragma unroll
            for (int k = 0; k < NK; k++)
                a = fmaf(s_z[i*NK + k], gW[NK*NEMB + k*NEMB + e], a);
            s_x[idx] += a;
        }
        __syncthreads();
        // 6. readout
        float part = (s_x[t] + s_x[t + 256]) * orbW[t & 15];
#pragma unroll
        for (int off = 32; off > 0; off >>= 1) part += __shfl_down(part, off, 64);
        if ((t & 63) == 0) s_red[t >> 6] = part;
        __syncthreads();
        if (t == 0) out[b] = s_red[0] + s_red[1] + s_red[2] + s_red[3];
        __syncthreads();
    }
}

extern "C" void kernel_launch(void* const* d_in, const int* in_sizes, int n_in,
                              void* d_out, int out_size, void* d_ws, size_t ws_size,
                              hipStream_t stream)
{
    char* ws = (char*)d_ws;
    __hip_bfloat16* w2 = (__hip_bfloat16*)ws;
    float* z1p = (float*)(ws + Z1P_OFF);
    float* zn1 = (float*)(ws + ZN1_OFF);
    float* zn2 = (float*)(ws + ZN2_OFF);

    jastrow_fused<<<NB + NB/4, 256, 0, stream>>>(
        (const float*)d_in[0],  (const float*)d_in[1],  (const float*)d_in[2],
        (const float*)d_in[3],  (const float*)d_in[4],  (const float*)d_in[5],
        (const float*)d_in[6],  (const float*)d_in[7],  (const float*)d_in[8],
        (const float*)d_in[9],  (const float*)d_in[10], (const float*)d_in[11],
        (const float*)d_in[12],
        w2, z1p, zn1, zn2, (float*)d_out);
}

// Round 7
// 271.647 us; speedup vs baseline: 1.3526x; 1.1006x over previous
//
#include <hip/hip_runtime.h>
#include <hip/hip_bf16.h>
#include <cstddef>

// JastrowNet, single fused kernel, R=2 rows/thread with FULL upfront row
// loads (R6 lesson: touching a 128-B edge row 8x spread across the MLP body
// thrashes L1/L2 -> 4.3x HBM overfetch; upfront ev[...] loads fetch once).
// Grid = 1280 blocks x 256 threads:
//   bid < 1024 : electron. b = bid>>1, c = bid&1 (0 same, 1 anti).
//                Thread t=(i16,j16): 2 rows = quadrant q=0,1 with
//                (qi=q, qj=c?1-q:q).
//   bid >= 1024: nuclear. bA = 2*(bid-1024). Thread t: row t (i=t>>3,m=t&7)
//                of batches bA, bA+1.
// Weights in LDS (broadcast ds_read_b128, 0 conflicts). R=2 shares every
// weight read across 2 rows -> 1 ds_read_b128 : 8 FMAs -> VALU-bound.
// Layer-1 reduces in-register to z1 partials (hx1 is spin-only); layer-2
// elec filters stored masked bf16; nuclear pre-reduced vs Y both layers.
// Last-arriving of the 3 contributors per batch (device-scope atomic,
// self-resetting counter — R4/R6-proven) runs the tiny update inline.
//
// Workspace: w2 bf16 [512][32][32][8] | z1p f32 [512][2][32][8]
//            | zn1 f32 [512][32][8] | zn2 f32 [512][32][8]

#define NB   512
#define NE   32
#define NA   8
#define NF   32
#define NH   16
#define NK   8
#define NEMB 16

#define Z1P_OFF  8388608u
#define ZN1_OFF  (Z1P_OFF + 1048576u)
#define ZN2_OFF  (ZN1_OFF + 524288u)

__device__ int g_cnt[NB];   // zero at load; winner self-resets each launch

__device__ __forceinline__ float ssp(float v){
    return fmaxf(v, 0.f) + __logf(1.f + __expf(-fabsf(v))) - 0.6931471805599453f;
}

extern "C" __global__ void __launch_bounds__(256, 3)
jastrow_fused(const float* __restrict__ edges_elec,
              const float* __restrict__ edges_nuc,
              const float* __restrict__ X_emb,
              const float* __restrict__ Yk,
              const float* __restrict__ wW1, const float* __restrict__ wb1,
              const float* __restrict__ wW2, const float* __restrict__ wb2,
              const float* __restrict__ hW,  const float* __restrict__ hb,
              const float* __restrict__ gW,  const float* __restrict__ gb,
              const float* __restrict__ orbW,
              __hip_bfloat16* __restrict__ w2,
              float* __restrict__ z1p,
              float* __restrict__ zn1, float* __restrict__ zn2,
              float* __restrict__ out)
{
    __shared__ __align__(16) float s_W1[2*NF*NH];   // this channel, layers 0,1
    __shared__ __align__(16) float s_b1[2*NH];
    __shared__ __align__(16) float s_W2[2*NH*NK];
    __shared__ __align__(16) float s_b2[2*NK];
    __shared__ float s_hx1[2*NK];    // layer-1 hx by spin (elec blocks)
    __shared__ float s_Y[NA*NK];     // nuclear embeddings (nuc blocks)
    __shared__ float s_x[NE*NEMB];   // phase B
    __shared__ float s_z[NE*NK];
    __shared__ float s_hx[NE*NK];
    __shared__ float s_red[4];
    __shared__ int   s_win;

    const int bid = blockIdx.x, t = threadIdx.x;
    const bool isNuc = (bid >= 2*NB);
    const int b  = bid >> 1;                      // elec batch (if elec)
    const int c  = bid & 1;                       // elec channel (if elec)
    const int cc = isNuc ? 2 : c;                 // weight channel index
    const int bA = isNuc ? 2*(bid - 2*NB) : b;    // first batch this block touches

    // ---- stage channel-cc weights (both layers) into LDS ----
    for (int idx = t; idx < 2*NF*NH; idx += 256){
        const int l = idx >> 9, r = idx & 511;
        s_W1[idx] = wW1[(l*3 + cc)*NF*NH + r];
    }
    if (t < 2*NH*NK){
        const int l = t >> 7, r = t & 127;
        s_W2[t] = wW2[(l*3 + cc)*NH*NK + r];
    }
    if (t < 2*NH){ const int l = t >> 4; s_b1[t] = wb1[(l*3 + cc)*NH + (t & 15)]; }
    if (t < 2*NK){ const int l = t >> 3; s_b2[t] = wb2[(l*3 + cc)*NK + (t & 7)]; }
    if (isNuc){
        if (t < NA*NK) s_Y[t] = Yk[t];
    } else if (t < 2*NK){
        const int sp = t >> 3, k = t & 7;
        float acc = hb[k];
#pragma unroll
        for (int e = 0; e < NEMB; e++)
            acc = fmaf(X_emb[sp*NEMB + e], hW[e*NK + k], acc);
        s_hx1[t] = ssp(acc);
    }
    __syncthreads();

    // ---- load both of this thread's rows fully into registers, upfront ----
    const int i16 = t >> 4, j16 = t & 15;
    float4 ev[2][8];
    {
        const float* r0;
        const float* r1;
        if (isNuc){
            r0 = edges_nuc + ((size_t)(bA + 0)*NE*NA + t) * NF;
            r1 = edges_nuc + ((size_t)(bA + 1)*NE*NA + t) * NF;
        } else {
            const int qj0 = c ? 1 : 0, qj1 = c ? 0 : 1;
            r0 = edges_elec + (((size_t)b*NE +      i16)*NE + qj0*16 + j16) * NF;
            r1 = edges_elec + (((size_t)b*NE + 16 + i16)*NE + qj1*16 + j16) * NF;
        }
#pragma unroll
        for (int qc = 0; qc < 8; qc++) ev[0][qc] = ((const float4*)r0)[qc];
#pragma unroll
        for (int qc = 0; qc < 8; qc++) ev[1][qc] = ((const float4*)r1)[qc];
    }

    // ================= Phase A: filter MLPs, both layers =================
#pragma unroll 1
    for (int l = 0; l < 2; l++){
        const float* W1 = s_W1 + l*NF*NH;
        const float* B1 = s_b1 + l*NH;
        const float* W2s = s_W2 + l*NH*NK;
        const float* B2 = s_b2 + l*NK;

        float h1[2][NH];
#pragma unroll
        for (int s = 0; s < 2; s++)
#pragma unroll
            for (int h = 0; h < NH; h++) h1[s][h] = B1[h];

#pragma unroll
        for (int qc = 0; qc < 8; qc++){
#pragma unroll
            for (int c4 = 0; c4 < 4; c4++){
                const float4* wr = (const float4*)(W1 + (qc*4 + c4)*NH);
                const float4 w0 = wr[0], w1 = wr[1], w2v = wr[2], w3 = wr[3];
#pragma unroll
                for (int s = 0; s < 2; s++){
                    const float ef = (c4 == 0) ? ev[s][qc].x : (c4 == 1) ? ev[s][qc].y
                                   : (c4 == 2) ? ev[s][qc].z : ev[s][qc].w;
                    h1[s][ 0] = fmaf(ef, w0.x, h1[s][ 0]);
                    h1[s][ 1] = fmaf(ef, w0.y, h1[s][ 1]);
                    h1[s][ 2] = fmaf(ef, w0.z, h1[s][ 2]);
                    h1[s][ 3] = fmaf(ef, w0.w, h1[s][ 3]);
                    h1[s][ 4] = fmaf(ef, w1.x, h1[s][ 4]);
                    h1[s][ 5] = fmaf(ef, w1.y, h1[s][ 5]);
                    h1[s][ 6] = fmaf(ef, w1.z, h1[s][ 6]);
                    h1[s][ 7] = fmaf(ef, w1.w, h1[s][ 7]);
                    h1[s][ 8] = fmaf(ef, w2v.x, h1[s][ 8]);
                    h1[s][ 9] = fmaf(ef, w2v.y, h1[s][ 9]);
                    h1[s][10] = fmaf(ef, w2v.z, h1[s][10]);
                    h1[s][11] = fmaf(ef, w2v.w, h1[s][11]);
                    h1[s][12] = fmaf(ef, w3.x, h1[s][12]);
                    h1[s][13] = fmaf(ef, w3.y, h1[s][13]);
                    h1[s][14] = fmaf(ef, w3.z, h1[s][14]);
                    h1[s][15] = fmaf(ef, w3.w, h1[s][15]);
                }
            }
        }
#pragma unroll
        for (int s = 0; s < 2; s++)
#pragma unroll
            for (int h = 0; h < NH; h++) h1[s][h] = ssp(h1[s][h]);

        float acc[2][NK];
#pragma unroll
        for (int s = 0; s < 2; s++)
#pragma unroll
            for (int k = 0; k < NK; k++) acc[s][k] = B2[k];
#pragma unroll
        for (int h = 0; h < NH; h++){
            const float4* wr = (const float4*)(W2s + h*NK);
            const float4 w0 = wr[0], w1 = wr[1];
#pragma unroll
            for (int s = 0; s < 2; s++){
                const float hv = h1[s][h];
                acc[s][0] = fmaf(hv, w0.x, acc[s][0]);
                acc[s][1] = fmaf(hv, w0.y, acc[s][1]);
                acc[s][2] = fmaf(hv, w0.z, acc[s][2]);
                acc[s][3] = fmaf(hv, w0.w, acc[s][3]);
                acc[s][4] = fmaf(hv, w1.x, acc[s][4]);
                acc[s][5] = fmaf(hv, w1.y, acc[s][5]);
                acc[s][6] = fmaf(hv, w1.z, acc[s][6]);
                acc[s][7] = fmaf(hv, w1.w, acc[s][7]);
            }
        }
#pragma unroll
        for (int s = 0; s < 2; s++)
#pragma unroll
            for (int k = 0; k < NK; k++) acc[s][k] = ssp(acc[s][k]);

        // ---- consume ----
        if (isNuc){
            const int i = t >> 3, m = t & 7;
            float* zn = (l == 0) ? zn1 : zn2;
#pragma unroll
            for (int s = 0; s < 2; s++){
                float pk[NK];
#pragma unroll
                for (int k = 0; k < NK; k++) pk[k] = acc[s][k] * s_Y[m*NK + k];
#pragma unroll
                for (int off = 4; off > 0; off >>= 1)
#pragma unroll
                    for (int k = 0; k < NK; k++) pk[k] += __shfl_down(pk[k], off, 8);
                if (m == 0){
#pragma unroll
                    for (int k = 0; k < NK; k++)
                        zn[((size_t)(bA + s)*NE + i)*NK + k] = pk[k];
                }
            }
        } else {
            const float msk = (c == 0 && i16 == j16) ? 0.f : 1.f;
            if (l == 0){
#pragma unroll
                for (int s = 0; s < 2; s++){
                    const int qj = c ? (1 - s) : s;
                    float pk[NK];
#pragma unroll
                    for (int k = 0; k < NK; k++)
                        pk[k] = acc[s][k] * msk * s_hx1[qj*NK + k];
#pragma unroll
                    for (int off = 8; off > 0; off >>= 1)
#pragma unroll
                        for (int k = 0; k < NK; k++) pk[k] += __shfl_down(pk[k], off, 16);
                    if (j16 == 0){
                        const int i = s*16 + i16;
#pragma unroll
                        for (int k = 0; k < NK; k++)
                            z1p[(((size_t)b*2 + c)*NE + i)*NK + k] = pk[k];
                    }
                }
            } else {
#pragma unroll
                for (int s = 0; s < 2; s++){
                    const int qj = c ? (1 - s) : s;
                    const int i = s*16 + i16, j = qj*16 + j16;
                    union { __hip_bfloat16 h[8]; uint4 u; } pack;
#pragma unroll
                    for (int k = 0; k < NK; k++)
                        pack.h[k] = __float2bfloat16(acc[s][k] * msk);
                    *(uint4*)&w2[((size_t)b*NE*NE + i*NE + j)*NK] = pack.u;
                }
            }
        }
    }

    // ---- completion handshake: 3 contributors per batch ----
    __threadfence();
    __syncthreads();
    if (t == 0){
        int mask = 0;
        const int nb = isNuc ? 2 : 1;
        for (int s = 0; s < nb; s++){
            const int old = atomicAdd(&g_cnt[bA + s], 1);
            if (old == 2){ mask |= 1 << s; atomicExch(&g_cnt[bA + s], 0); }
        }
        s_win = mask;
    }
    __syncthreads();
    const int mask = s_win;
    if (!mask) return;
    __threadfence();   // acquire: other contributors' writes now visible

    // ================= Phase B: per-batch sequential update =================
    for (int s = 0; s < 2; s++){
        if (!(mask & (1 << s))) continue;
        const int bb = bA + s;
        // 1. z1 = partials + nuclear
        s_z[t] = z1p[((size_t)bb*2 + 0)*NE*NK + t]
               + z1p[((size_t)bb*2 + 1)*NE*NK + t]
               + zn1[(size_t)bb*NE*NK + t];
        __syncthreads();
        // 2. x1 = x0 + z1 @ gW0 + gb0
#pragma unroll
        for (int q = 0; q < 2; q++){
            const int idx = q*256 + t, i = idx >> 4, e = idx & 15;
            float a = gb[e];
#pragma unroll
            for (int k = 0; k < NK; k++)
                a = fmaf(s_z[i*NK + k], gW[k*NEMB + e], a);
            s_x[idx] = X_emb[(i >> 4)*NEMB + e] + a;
        }
        __syncthreads();
        // 3. hx2 = ssp(x1 @ hW1 + hb1)
        {
            const int i = t >> 3, k = t & 7;
            float a = hb[NK + k];
#pragma unroll
            for (int e = 0; e < NEMB; e++)
                a = fmaf(s_x[i*NEMB + e], hW[NEMB*NK + e*NK + k], a);
            s_hx[t] = ssp(a);
        }
        __syncthreads();
        // 4. z2[i,k] = sum_j w2[i,j,k]*hx2[j,k] + zn2
        {
            const int i = t >> 3, k = t & 7;
            const __hip_bfloat16* wrow = w2 + ((size_t)bb*NE*NE + i*NE)*NK + k;
            float a = zn2[(size_t)bb*NE*NK + t];
#pragma unroll
            for (int j = 0; j < NE; j++)
                a = fmaf(__bfloat162float(wrow[j*NK]), s_hx[j*NK + k], a);
            s_z[t] = a;
        }
        __syncthreads();
        // 5. x2 = x1 + z2 @ gW1 + gb1
#pragma unroll
        for (int q = 0; q < 2; q++){
            const int idx = q*256 + t, i = idx >> 4, e = idx & 15;
            float a = gb[NEMB + e];
#pragma unroll
            for (int k = 0; k < NK; k++)
                a = fmaf(s_z[i*NK + k], gW[NK*NEMB + k*NEMB + e], a);
            s_x[idx] += a;
        }
        __syncthreads();
        // 6. readout
        float part = (s_x[t] + s_x[t + 256]) * orbW[t & 15];
#pragma unroll
        for (int off = 32; off > 0; off >>= 1) part += __shfl_down(part, off, 64);
        if ((t & 63) == 0) s_red[t >> 6] = part;
        __syncthreads();
        if (t == 0) out[bb] = s_red[0] + s_red[1] + s_red[2] + s_red[3];
        __syncthreads();
    }
}

extern "C" void kernel_launch(void* const* d_in, const int* in_sizes, int n_in,
                              void* d_out, int out_size, void* d_ws, size_t ws_size,
                              hipStream_t stream)
{
    char* ws = (char*)d_ws;
    __hip_bfloat16* w2 = (__hip_bfloat16*)ws;
    float* z1p = (float*)(ws + Z1P_OFF);
    float* zn1 = (float*)(ws + ZN1_OFF);
    float* zn2 = (float*)(ws + ZN2_OFF);

    jastrow_fused<<<2*NB + NB/2, 256, 0, stream>>>(
        (const float*)d_in[0],  (const float*)d_in[1],  (const float*)d_in[2],
        (const float*)d_in[3],  (const float*)d_in[4],  (const float*)d_in[5],
        (const float*)d_in[6],  (const float*)d_in[7],  (const float*)d_in[8],
        (const float*)d_in[9],  (const float*)d_in[10], (const float*)d_in[11],
        (const float*)d_in[12],
        w2, z1p, zn1, zn2, (float*)d_out);
}

// Round 8
// 211.081 us; speedup vs baseline: 1.7407x; 1.2869x over previous
//
#include <hip/hip_runtime.h>
#include <hip/hip_bf16.h>
#include <cstddef>

// JastrowNet, two kernels (R3-proven shape), fine-grained K1.
// K1 grid = 2560 blocks x 256 threads, one (batch, channel, LAYER) per block:
//   bid < 2048 : electron. b = bid>>2, c = (bid>>1)&1 (0 same, 1 anti),
//                l = bid&1. Thread (i16,j16) handles R=2 rows:
//                s=0: (i16, qj0*16+j16), s=1: (16+i16, qj1*16+j16),
//                qj(s) = c ? 1-s : s.
//   bid >= 2048: nuclear. idx = bid-2048, pair = idx>>1, l = idx&1,
//                bA = 2*pair. Thread t: row t of batches bA, bA+1.
// Rationale (R7 post-mortem): VALU-busy time is ~39 us in every variant; what
// differs is stall fraction, which tracks resident-wave count. 2560 small
// blocks with low VGPR (R3's recipe) sustained 2.3x the issue rate of 1280
// big blocks. R=2 keeps the LDS amortization (160 ds_read_b128/wave-layer);
// layer-split halves per-block registers and duration.
// h1/W2 accumulate in float2 ext-vectors -> v_pk_fma_f32 (2 FMA/inst).
// Layer-1(l=0) output reduces directly to z1 partials (hx1 is spin-only);
// l=1 electron filters stored masked bf16; nuclear pre-reduced vs Y.
// K2 = R3's proven per-batch sequential update.
//
// Workspace: w2 bf16 [512][32][32][8] | z1p f32 [512][2][32][8]
//            | zn1 f32 [512][32][8] | zn2 f32 [512][32][8]

#define NB   512
#define NE   32
#define NA   8
#define NF   32
#define NH   16
#define NK   8
#define NEMB 16

#define Z1P_OFF  8388608u
#define ZN1_OFF  (Z1P_OFF + 1048576u)
#define ZN2_OFF  (ZN1_OFF + 524288u)

typedef float v2f __attribute__((ext_vector_type(2)));

__device__ __forceinline__ float ssp(float v){
    return fmaxf(v, 0.f) + __logf(1.f + __expf(-fabsf(v))) - 0.6931471805599453f;
}

// Two 32-feature rows through the 32->16->8 ssp MLP (one layer).
// Weights from LDS (wave-broadcast, conflict-free); acc in float2 pairs.
__device__ __forceinline__ void mlp2(const float* __restrict__ rA,
                                     const float* __restrict__ rB,
                                     const float* __restrict__ sW1,
                                     const float* __restrict__ sb1,
                                     const float* __restrict__ sW2,
                                     const float* __restrict__ sb2,
                                     float wout[2][NK])
{
    v2f h[2][8];
    const v2f* b1 = (const v2f*)sb1;
#pragma unroll
    for (int u = 0; u < 8; u++){ h[0][u] = b1[u]; h[1][u] = b1[u]; }

#pragma unroll
    for (int q = 0; q < 8; q++){
        const float4 fA = ((const float4*)rA)[q];
        const float4 fB = ((const float4*)rB)[q];
#pragma unroll
        for (int c4 = 0; c4 < 4; c4++){
            const v2f* wr = (const v2f*)(sW1 + (q*4 + c4)*NH);
            const float eA = (c4==0)?fA.x:(c4==1)?fA.y:(c4==2)?fA.z:fA.w;
            const float eB = (c4==0)?fB.x:(c4==1)?fB.y:(c4==2)?fB.z:fB.w;
            const v2f vA = {eA, eA}, vB = {eB, eB};
#pragma unroll
            for (int u = 0; u < 8; u++){
                const v2f wv = wr[u];
                h[0][u] = __builtin_elementwise_fma(vA, wv, h[0][u]);
                h[1][u] = __builtin_elementwise_fma(vB, wv, h[1][u]);
            }
        }
    }
#pragma unroll
    for (int s = 0; s < 2; s++)
#pragma unroll
        for (int u = 0; u < 8; u++){
            h[s][u].x = ssp(h[s][u].x);
            h[s][u].y = ssp(h[s][u].y);
        }

    v2f a[2][4];
    const v2f* b2 = (const v2f*)sb2;
#pragma unroll
    for (int u = 0; u < 4; u++){ a[0][u] = b2[u]; a[1][u] = b2[u]; }
#pragma unroll
    for (int u = 0; u < 8; u++){
#pragma unroll
        for (int half = 0; half < 2; half++){
            const int hh = 2*u + half;
            const v2f* wr = (const v2f*)(sW2 + hh*NK);
            const float hA = half ? h[0][u].y : h[0][u].x;
            const float hB = half ? h[1][u].y : h[1][u].x;
            const v2f vA = {hA, hA}, vB = {hB, hB};
#pragma unroll
            for (int u2 = 0; u2 < 4; u2++){
                const v2f wv = wr[u2];
                a[0][u2] = __builtin_elementwise_fma(vA, wv, a[0][u2]);
                a[1][u2] = __builtin_elementwise_fma(vB, wv, a[1][u2]);
            }
        }
    }
#pragma unroll
    for (int s = 0; s < 2; s++)
#pragma unroll
        for (int u = 0; u < 4; u++){
            wout[s][2*u]   = ssp(a[s][u].x);
            wout[s][2*u+1] = ssp(a[s][u].y);
        }
}

// ---------------- K1: filters ----------------
extern "C" __global__ void __launch_bounds__(256, 6)
filters_kernel(const float* __restrict__ edges_elec,
               const float* __restrict__ edges_nuc,
               const float* __restrict__ X_emb,
               const float* __restrict__ Yk,
               const float* __restrict__ wW1, const float* __restrict__ wb1,
               const float* __restrict__ wW2, const float* __restrict__ wb2,
               const float* __restrict__ hW,  const float* __restrict__ hb,
               __hip_bfloat16* __restrict__ w2out,
               float* __restrict__ z1p,
               float* __restrict__ zn1, float* __restrict__ zn2)
{
    __shared__ __align__(16) float s_W1[NF*NH];   // one layer, one channel
    __shared__ __align__(16) float s_b1[NH];
    __shared__ __align__(16) float s_W2[NH*NK];
    __shared__ __align__(16) float s_b2[NK];
    __shared__ float s_hx1[2*NK];    // layer-1 hx by spin (elec l=0)
    __shared__ float s_Y[NA*NK];     // nuclear embeddings (nuc blocks)

    const int bid = blockIdx.x, t = threadIdx.x;
    const bool isNuc = (bid >= 4*NB);
    int b, c, l, bA;
    if (isNuc){
        const int idx = bid - 4*NB;
        l = idx & 1; bA = 2*(idx >> 1); b = bA; c = 0;
    } else {
        b = bid >> 2; c = (bid >> 1) & 1; l = bid & 1; bA = b;
    }
    const int cc = isNuc ? 2 : c;

    // ---- stage this (layer, channel)'s weights into LDS ----
    for (int i2 = t; i2 < NF*NH; i2 += 256) s_W1[i2] = wW1[(l*3 + cc)*NF*NH + i2];
    if (t < NH*NK) s_W2[t] = wW2[(l*3 + cc)*NH*NK + t];
    if (t < NH)    s_b1[t] = wb1[(l*3 + cc)*NH + t];
    if (t < NK)    s_b2[t] = wb2[(l*3 + cc)*NK + t];
    if (isNuc){
        if (t < NA*NK) s_Y[t] = Yk[t];
    } else if (l == 0 && t < 2*NK){
        // hx1[spin][k] = ssp(X_emb[spin] @ hW[0] + hb[0])
        const int sp = t >> 3, k = t & 7;
        float acc = hb[k];
#pragma unroll
        for (int e = 0; e < NEMB; e++)
            acc = fmaf(X_emb[sp*NEMB + e], hW[e*NK + k], acc);
        s_hx1[t] = ssp(acc);
    }
    __syncthreads();

    const int i16 = t >> 4, j16 = t & 15;
    const float* rA;
    const float* rB;
    if (isNuc){
        rA = edges_nuc + ((size_t)(bA + 0)*NE*NA + t) * NF;
        rB = edges_nuc + ((size_t)(bA + 1)*NE*NA + t) * NF;
    } else {
        const int qj0 = c ? 1 : 0, qj1 = c ? 0 : 1;
        rA = edges_elec + (((size_t)b*NE +      i16)*NE + qj0*16 + j16) * NF;
        rB = edges_elec + (((size_t)b*NE + 16 + i16)*NE + qj1*16 + j16) * NF;
    }

    float w[2][NK];
    mlp2(rA, rB, s_W1, s_b1, s_W2, s_b2, w);

    // ---- consume ----
    if (isNuc){
        const int i = t >> 3, m = t & 7;
        float* zn = (l == 0) ? zn1 : zn2;
#pragma unroll
        for (int s = 0; s < 2; s++){
            float pk[NK];
#pragma unroll
            for (int k = 0; k < NK; k++) pk[k] = w[s][k] * s_Y[m*NK + k];
#pragma unroll
            for (int off = 4; off > 0; off >>= 1)
#pragma unroll
                for (int k = 0; k < NK; k++) pk[k] += __shfl_down(pk[k], off, 8);
            if (m == 0){
#pragma unroll
                for (int k = 0; k < NK; k++)
                    zn[((size_t)(bA + s)*NE + i)*NK + k] = pk[k];
            }
        }
    } else {
        const float msk = (c == 0 && i16 == j16) ? 0.f : 1.f;
        if (l == 0){
#pragma unroll
            for (int s = 0; s < 2; s++){
                const int qj = c ? (1 - s) : s;
                float pk[NK];
#pragma unroll
                for (int k = 0; k < NK; k++)
                    pk[k] = w[s][k] * msk * s_hx1[qj*NK + k];
#pragma unroll
                for (int off = 8; off > 0; off >>= 1)
#pragma unroll
                    for (int k = 0; k < NK; k++) pk[k] += __shfl_down(pk[k], off, 16);
                if (j16 == 0){
                    const int i = s*16 + i16;
#pragma unroll
                    for (int k = 0; k < NK; k++)
                        z1p[(((size_t)b*2 + c)*NE + i)*NK + k] = pk[k];
                }
            }
        } else {
#pragma unroll
            for (int s = 0; s < 2; s++){
                const int qj = c ? (1 - s) : s;
                const int i = s*16 + i16, j = qj*16 + j16;
                union { __hip_bfloat16 h[8]; uint4 u; } pack;
#pragma unroll
                for (int k = 0; k < NK; k++)
                    pack.h[k] = __float2bfloat16(w[s][k] * msk);
                *(uint4*)&w2out[((size_t)b*NE*NE + i*NE + j)*NK] = pack.u;
            }
        }
    }
}

// ---------------- K2: per-batch sequential update (R3-proven) ----------------
extern "C" __global__ void __launch_bounds__(256, 4)
update_kernel(const float* __restrict__ X_emb,
              const float* __restrict__ hW,  const float* __restrict__ hb,
              const float* __restrict__ gW,  const float* __restrict__ gb,
              const float* __restrict__ orbW,
              const __hip_bfloat16* __restrict__ w2,
              const float* __restrict__ z1p,
              const float* __restrict__ zn1, const float* __restrict__ zn2,
              float* __restrict__ out)
{
    __shared__ float s_x[NE*NEMB];
    __shared__ float s_z[NE*NK];
    __shared__ float s_hx[NE*NK];
    __shared__ float s_gW[2*NK*NEMB];
    __shared__ float s_gb[2*NEMB];
    __shared__ float s_hW1[NEMB*NK];
    __shared__ float s_hb1[NK];
    __shared__ float s_orb[NEMB];
    __shared__ float s_red[4];

    const int b = blockIdx.x, t = threadIdx.x;

    s_gW[t] = gW[t];
    if (t < 2*NEMB)  s_gb[t]  = gb[t];
    if (t < NEMB*NK) s_hW1[t] = hW[NEMB*NK + t];
    if (t < NK)      s_hb1[t] = hb[NK + t];
    if (t < NEMB)    s_orb[t] = orbW[t];
    {
        const int i = t >> 3, k = t & 7;
        s_z[t] = z1p[(((size_t)b*2 + 0)*NE + i)*NK + k]
               + z1p[(((size_t)b*2 + 1)*NE + i)*NK + k]
               + zn1[((size_t)b*NE + i)*NK + k];
    }
    __syncthreads();
#pragma unroll
    for (int q = 0; q < 2; q++){
        const int idx = q*256 + t, i = idx >> 4, e = idx & 15;
        float acc = s_gb[e];
#pragma unroll
        for (int k = 0; k < NK; k++)
            acc = fmaf(s_z[i*NK + k], s_gW[k*NEMB + e], acc);
        s_x[idx] = X_emb[(i >> 4)*NEMB + e] + acc;
    }
    __syncthreads();
    {
        const int i = t >> 3, k = t & 7;
        float acc = s_hb1[k];
#pragma unroll
        for (int e = 0; e < NEMB; e++)
            acc = fmaf(s_x[i*NEMB + e], s_hW1[e*NK + k], acc);
        s_hx[t] = ssp(acc);
    }
    __syncthreads();
    {
        const int i16 = t >> 4, j16 = t & 15;
#pragma unroll
        for (int qh = 0; qh < 2; qh++){
            const int i = qh*16 + i16;
            float zacc[NK];
#pragma unroll
            for (int k = 0; k < NK; k++) zacc[k] = 0.f;
#pragma unroll
            for (int qj = 0; qj < 2; qj++){
                const int j = qj*16 + j16;
                union { uint4 u; __hip_bfloat16 h[8]; } raw;
                raw.u = *(const uint4*)&w2[((size_t)b*NE*NE + i*NE + j)*NK];
                float pk[NK];
#pragma unroll
                for (int k = 0; k < NK; k++)
                    pk[k] = __bfloat162float(raw.h[k]) * s_hx[j*NK + k];
#pragma unroll
                for (int off = 8; off > 0; off >>= 1)
#pragma unroll
                    for (int k = 0; k < NK; k++) pk[k] += __shfl_down(pk[k], off, 16);
#pragma unroll
                for (int k = 0; k < NK; k++) zacc[k] += pk[k];
            }
            if (j16 == 0){
#pragma unroll
                for (int k = 0; k < NK; k++) s_z[i*NK + k] = zacc[k];
            }
        }
    }
    __syncthreads();
    { const int i = t >> 3, k = t & 7; s_z[t] += zn2[((size_t)b*NE + i)*NK + k]; }
    __syncthreads();
#pragma unroll
    for (int q = 0; q < 2; q++){
        const int idx = q*256 + t, i = idx >> 4, e = idx & 15;
        float acc = s_gb[NEMB + e];
#pragma unroll
        for (int k = 0; k < NK; k++)
            acc = fmaf(s_z[i*NK + k], s_gW[NK*NEMB + k*NEMB + e], acc);
        s_x[idx] += acc;
    }
    __syncthreads();
    float part = (s_x[t] + s_x[t + 256]) * s_orb[t & 15];
#pragma unroll
    for (int off = 32; off > 0; off >>= 1) part += __shfl_down(part, off, 64);
    if ((t & 63) == 0) s_red[t >> 6] = part;
    __syncthreads();
    if (t == 0) out[b] = s_red[0] + s_red[1] + s_red[2] + s_red[3];
}

extern "C" void kernel_launch(void* const* d_in, const int* in_sizes, int n_in,
                              void* d_out, int out_size, void* d_ws, size_t ws_size,
                              hipStream_t stream)
{
    const float* edges_elec = (const float*)d_in[0];
    const float* edges_nuc  = (const float*)d_in[1];
    const float* X_emb      = (const float*)d_in[2];
    const float* Yk         = (const float*)d_in[3];
    const float* wW1        = (const float*)d_in[4];
    const float* wb1        = (const float*)d_in[5];
    const float* wW2        = (const float*)d_in[6];
    const float* wb2        = (const float*)d_in[7];
    const float* hW         = (const float*)d_in[8];
    const float* hb         = (const float*)d_in[9];
    const float* gW         = (const float*)d_in[10];
    const float* gb         = (const float*)d_in[11];
    const float* orbW       = (const float*)d_in[12];

    char* ws = (char*)d_ws;
    __hip_bfloat16* w2 = (__hip_bfloat16*)ws;
    float* z1p = (float*)(ws + Z1P_OFF);
    float* zn1 = (float*)(ws + ZN1_OFF);
    float* zn2 = (float*)(ws + ZN2_OFF);

    filters_kernel<<<4*NB + NB, 256, 0, stream>>>(
        edges_elec, edges_nuc, X_emb, Yk, wW1, wb1, wW2, wb2, hW, hb,
        w2, z1p, zn1, zn2);
    update_kernel<<<NB, 256, 0, stream>>>(
        X_emb, hW, hb, gW, gb, orbW, w2, z1p, zn1, zn2, (float*)d_out);
}